// Round 13
// baseline (204.608 us; speedup 1.0000x reference)
//
#include <hip/hip_runtime.h>
#include <hip/hip_bf16.h>
#include <cstdint>

// GraphSAGE 3-layer + edge predictor (10 dispatches: memset, prep+bucket,
// eagg+proj1, [gath(+pe1/2/3) -> apply+proj]x3, edge_out).
//   segsum(concat(h[src],e)@Wm.T+bm,dst) = segsum(ph[src]) + pe
//     ph = h@Wmh.T (commutes past segsum), pe = eagg@Wme.T + deg*bm
//   eagg/deg layer-independent. ph bf16-hi (3.2MB, L2-resident gather table).
// Dispatch-merge rules (R4/R8/R10/R11): 1 node = 1 wave = 1 block for
// eagg/gather; never move wide parallel work into the per-layer serial path;
// independent tile jobs may ride a latency-bound dispatch as extra blocks.
// proj1 rides eagg; pe1/2/3 ride gather-1; prep rides bucket (independent).
// MFMA 16x16x32 bf16 hi/lo split (3 MFMA, err ~2^-17); A and W packed with
// the SAME (lane,elem)->k map.

static inline int cdiv(int a, int b) { return (a + b - 1) / b; }

#define NN 10000
#define NE 320000
#define MTB 313  // cdiv(NN,32)
#define MD 192   // bucket capacity per node
#define NBK 1250 // cdiv(NE,256) bucket blocks

typedef __attribute__((ext_vector_type(8))) short bf16x8;
typedef __attribute__((ext_vector_type(4))) float f32x4;

__device__ __forceinline__ ushort f2bf(float x) {
  union { float f; unsigned u; } c; c.f = x;
  unsigned r = c.u + 0x7FFFu + ((c.u >> 16) & 1u);
  return (ushort)(r >> 16);
}
__device__ __forceinline__ float bf2f(unsigned h) {
  union { unsigned u; float f; } c; c.u = h << 16;
  return c.f;
}
__device__ __forceinline__ f32x4 mfma3(bf16x8 ah, bf16x8 al, bf16x8 bh, bf16x8 bl,
                                       f32x4 acc) {
  acc = __builtin_amdgcn_mfma_f32_16x16x32_bf16(ah, bh, acc, 0, 0, 0);
  acc = __builtin_amdgcn_mfma_f32_16x16x32_bf16(al, bh, acc, 0, 0, 0);
  acc = __builtin_amdgcn_mfma_f32_16x16x32_bf16(ah, bl, acc, 0, 0, 0);
  return acc;
}
// load 8 consecutive fp32 -> hi/lo bf16 fragments
__device__ __forceinline__ void ld32frag(const float* p, bf16x8& h, bf16x8& l) {
  float4 x0 = *(const float4*)p;
  float4 x1 = *(const float4*)(p + 4);
  float v[8] = {x0.x, x0.y, x0.z, x0.w, x1.x, x1.y, x1.z, x1.w};
#pragma unroll
  for (int j = 0; j < 8; ++j) {
    ushort hh = f2bf(v[j]);
    h[j] = (short)hh;
    l[j] = (short)f2bf(v[j] - bf2f(hh));
  }
}
// packed-A LDS tile: [plane][kt][q][row32][8] bf16; float4-wide write
__device__ __forceinline__ void wpack4(ushort* lds, int base, int KT, int row,
                                       int k0, float4 v) {
  int idx0 = base + ((k0 >> 5) * 4 + ((k0 >> 3) & 3)) * 256 + row * 8 + (k0 & 7);
  int idx1 = idx0 + KT * 1024;
  ushort h0 = f2bf(v.x), h1 = f2bf(v.y), h2 = f2bf(v.z), h3 = f2bf(v.w);
  uint2 uh, ul;
  uh.x = (unsigned)h0 | ((unsigned)h1 << 16);
  uh.y = (unsigned)h2 | ((unsigned)h3 << 16);
  ushort l0 = f2bf(v.x - bf2f(h0)), l1 = f2bf(v.y - bf2f(h1));
  ushort l2 = f2bf(v.z - bf2f(h2)), l3 = f2bf(v.w - bf2f(h3));
  ul.x = (unsigned)l0 | ((unsigned)l1 << 16);
  ul.y = (unsigned)l2 | ((unsigned)l3 << 16);
  *reinterpret_cast<uint2*>(&lds[idx0]) = uh;
  *reinterpret_cast<uint2*>(&lds[idx1]) = ul;
}
__device__ __forceinline__ bf16x8 rfrag(const ushort* lds, int base, int KT,
                                        int plane, int kt, int lane, int mh) {
  int idx = base + ((plane * KT + kt) * 4 + (lane >> 4)) * 256 +
            ((lane & 15) + 16 * mh) * 8;
  return *reinterpret_cast<const bf16x8*>(&lds[idx]);
}

// ---------------- prep W packs + bucket build (merged; fill pre-zeroed) -------
struct WDesc {
  const float* W; ushort* hi; ushort* lo;
  int dout, KA, KApad, KB, Korig, NG16, KT, pred;
};
struct PrepArgs {
  WDesc d[7];
};

__global__ __launch_bounds__(256) void k_prepbucket(PrepArgs P,
                                                    const int* __restrict__ src,
                                                    const int* __restrict__ dst,
                                                    int* __restrict__ fill,
                                                    int2* __restrict__ bk) {
  if (blockIdx.x < NBK) {  // bucket part
    int e = blockIdx.x * 256 + threadIdx.x;
    if (e < NE) {
      int d = dst[e];
      int pos = atomicAdd(&fill[d], 1);
      if (pos < MD) bk[d * MD + pos] = make_int2(e, src[e]);
    }
    return;
  }
  // W-pack part: 7 descriptors x 40 blocks
  int b = blockIdx.x - NBK;
  const WDesc d = P.d[b / 40];
  int tid = (b % 40) * 256 + threadIdx.x;
  if (tid >= d.KT * d.NG16 * 64) return;
  int lane = tid & 63;
  int g = (tid >> 6) % d.NG16;
  int t = (tid >> 6) / d.NG16;
  int col = g * 16 + (lane & 15);
  int kbase = t * 32 + ((lane >> 4) * 8);
  size_t o = (size_t)tid * 8;
#pragma unroll
  for (int j = 0; j < 8; ++j) {
    int kk = kbase + j;
    float w = 0.f;
    if (!d.pred) {
      if (col < d.dout) {
        if (kk < d.KApad) { if (kk < d.KA) w = d.W[(size_t)col * d.Korig + kk]; }
        else { int kb = kk - d.KApad; if (kb < d.KB) w = d.W[(size_t)col * d.Korig + d.KA + kb]; }
      }
    } else {
      if (col < 15) w = d.W[(size_t)col * 256 + kk];
      else if (col < 30) w = d.W[(size_t)(col - 15) * 256 + 128 + kk];
    }
    ushort h = f2bf(w);
    d.hi[o + j] = h;
    d.lo[o + j] = f2bf(w - bf2f(h));
  }
}

// ---------------- eagg (1 wave/node) + proj1 tiles (extra blocks) ----------
__global__ __launch_bounds__(64) void k_eaggproj(
    const float* __restrict__ efeats, const int2* __restrict__ bk,
    const int* __restrict__ fill, const float* __restrict__ nfeats,
    const ushort* __restrict__ Wm1h, const ushort* __restrict__ Wm1l,
    ushort* __restrict__ ehi, ushort* __restrict__ elo,
    float* __restrict__ deg, ushort* __restrict__ ph1) {
  const int lane = threadIdx.x;
  if (blockIdx.x < NN) {
    const int d = blockIdx.x;
    const int half = lane >> 5, cl = lane & 31;
    const int cntd = fill[d];
    const int n = min(cntd, MD);
    const int s = d * MD, t = s + n;
    float4 acc[8];
#pragma unroll
    for (int u = 0; u < 8; ++u) acc[u] = make_float4(0.f, 0.f, 0.f, 0.f);
    int j = s;
    for (; j + 15 < t; j += 16) {
#pragma unroll
      for (int u = 0; u < 8; ++u) {
        int e0 = bk[j + 2 * u + half].x;
        float4 v = *(const float4*)(efeats + (size_t)e0 * 128 + cl * 4);
        acc[u].x += v.x; acc[u].y += v.y; acc[u].z += v.z; acc[u].w += v.w;
      }
    }
    for (; j + 1 < t; j += 2) {
      int e0 = bk[j + half].x;
      float4 v = *(const float4*)(efeats + (size_t)e0 * 128 + cl * 4);
      acc[0].x += v.x; acc[0].y += v.y; acc[0].z += v.z; acc[0].w += v.w;
    }
    if (j < t && half == 0) {
      int e0 = bk[j].x;
      float4 v = *(const float4*)(efeats + (size_t)e0 * 128 + cl * 4);
      acc[0].x += v.x; acc[0].y += v.y; acc[0].z += v.z; acc[0].w += v.w;
    }
#pragma unroll
    for (int u = 4; u > 0; u >>= 1)
#pragma unroll
      for (int w = 0; w < u; ++w) {
        acc[w].x += acc[w + u].x; acc[w].y += acc[w + u].y;
        acc[w].z += acc[w + u].z; acc[w].w += acc[w + u].w;
      }
    float4 sm = acc[0];
    sm.x += __shfl_xor(sm.x, 32);
    sm.y += __shfl_xor(sm.y, 32);
    sm.z += __shfl_xor(sm.z, 32);
    sm.w += __shfl_xor(sm.w, 32);
    if (lane < 32) {
      size_t o = (size_t)d * 128 + cl * 4;
      ushort h0 = f2bf(sm.x), h1 = f2bf(sm.y), h2 = f2bf(sm.z), h3 = f2bf(sm.w);
      uint2 uh, ul;
      uh.x = (unsigned)h0 | ((unsigned)h1 << 16);
      uh.y = (unsigned)h2 | ((unsigned)h3 << 16);
      ul.x = (unsigned)f2bf(sm.x - bf2f(h0)) | ((unsigned)f2bf(sm.y - bf2f(h1)) << 16);
      ul.y = (unsigned)f2bf(sm.z - bf2f(h2)) | ((unsigned)f2bf(sm.w - bf2f(h3)) << 16);
      *(uint2*)(ehi + o) = uh;
      *(uint2*)(elo + o) = ul;
    }
    if (lane == 0) deg[d] = (float)cntd;
    return;
  }
  // ---- proj1 tile: ph1 = nfeats @ Wm1(h-part), bf16-hi ----
  const int p = blockIdx.x - NN;
  const int ng0 = (p % 5) * 2;
  const int row0 = (p / 5) * 32;
  const int rA = lane & 15, kl = (lane >> 4) * 8, colL = lane & 15;
  const int r0 = min(row0 + rA, NN - 1), r1 = min(row0 + 16 + rA, NN - 1);
  f32x4 a00 = {0.f, 0.f, 0.f, 0.f}, a01 = {0.f, 0.f, 0.f, 0.f};
  f32x4 a10 = {0.f, 0.f, 0.f, 0.f}, a11 = {0.f, 0.f, 0.f, 0.f};
#pragma unroll
  for (int kt = 0; kt < 4; ++kt) {
    bf16x8 a0h, a0l, a1h, a1l;
    ld32frag(nfeats + (size_t)r0 * 128 + kt * 32 + kl, a0h, a0l);
    ld32frag(nfeats + (size_t)r1 * 128 + kt * 32 + kl, a1h, a1l);
    size_t wb = ((size_t)(kt * 10 + ng0) * 64 + lane) * 8;
    bf16x8 b0h = *(const bf16x8*)(Wm1h + wb), b0l = *(const bf16x8*)(Wm1l + wb);
    bf16x8 b1h = *(const bf16x8*)(Wm1h + wb + 512), b1l = *(const bf16x8*)(Wm1l + wb + 512);
    a00 = mfma3(a0h, a0l, b0h, b0l, a00);
    a01 = mfma3(a0h, a0l, b1h, b1l, a01);
    a10 = mfma3(a1h, a1l, b0h, b0l, a10);
    a11 = mfma3(a1h, a1l, b1h, b1l, a11);
  }
#pragma unroll
  for (int ms = 0; ms < 2; ++ms) {
    const f32x4 aN0 = ms ? a10 : a00;
    const f32x4 aN1 = ms ? a11 : a01;
#pragma unroll
    for (int reg = 0; reg < 4; ++reg) {
      int row = row0 + ms * 16 + (lane >> 4) * 4 + reg;
      if (row >= NN) continue;
#pragma unroll
      for (int ns = 0; ns < 2; ++ns) {
        int col = (ng0 + ns) * 16 + colL;
        float v = ns ? aN1[reg] : aN0[reg];
        ph1[(size_t)row * 160 + col] = f2bf(col < 152 ? v : 0.f);
      }
    }
  }
}

// ---------------- gather (pure f32 sum) + optional pe tiles ----------------
template <int WP, bool PE>
__global__ __launch_bounds__(64) void k_gath(
    const ushort* __restrict__ ph, const int2* __restrict__ bk,
    const int* __restrict__ fill, float* __restrict__ gsum,
    const ushort* __restrict__ eah, const ushort* __restrict__ eal,
    const ushort* __restrict__ pW1h, const ushort* __restrict__ pW1l,
    const ushort* __restrict__ pW2h, const ushort* __restrict__ pW2l,
    const ushort* __restrict__ pW3h, const ushort* __restrict__ pW3l,
    const float* __restrict__ bm1, const float* __restrict__ bm2,
    const float* __restrict__ bm3, const float* __restrict__ deg,
    float* __restrict__ pe1, float* __restrict__ pe2, float* __restrict__ pe3) {
  const int lane = threadIdx.x;
  if (!PE || blockIdx.x < NN) {
    constexpr int QUADS = WP / 4;  // 40 or 32 active lanes
    const int d = blockIdx.x;
    const int n = min(fill[d], MD);
    const int s = d * MD, t = s + n;
    float4 a0 = {0.f, 0.f, 0.f, 0.f}, a1 = a0, a2 = a0, a3 = a0;
    int j = s;
    for (; j + 3 < t; j += 4) {
      int s0 = bk[j].y, s1 = bk[j + 1].y, s2 = bk[j + 2].y, s3 = bk[j + 3].y;
      if (lane < QUADS) {
        uint2 u0 = *(const uint2*)(ph + (size_t)s0 * WP + 4 * lane);
        uint2 u1 = *(const uint2*)(ph + (size_t)s1 * WP + 4 * lane);
        uint2 u2 = *(const uint2*)(ph + (size_t)s2 * WP + 4 * lane);
        uint2 u3 = *(const uint2*)(ph + (size_t)s3 * WP + 4 * lane);
        a0.x += bf2f(u0.x & 0xffffu); a0.y += bf2f(u0.x >> 16);
        a0.z += bf2f(u0.y & 0xffffu); a0.w += bf2f(u0.y >> 16);
        a1.x += bf2f(u1.x & 0xffffu); a1.y += bf2f(u1.x >> 16);
        a1.z += bf2f(u1.y & 0xffffu); a1.w += bf2f(u1.y >> 16);
        a2.x += bf2f(u2.x & 0xffffu); a2.y += bf2f(u2.x >> 16);
        a2.z += bf2f(u2.y & 0xffffu); a2.w += bf2f(u2.y >> 16);
        a3.x += bf2f(u3.x & 0xffffu); a3.y += bf2f(u3.x >> 16);
        a3.z += bf2f(u3.y & 0xffffu); a3.w += bf2f(u3.y >> 16);
      }
    }
    for (; j < t; ++j) {
      int s0 = bk[j].y;
      if (lane < QUADS) {
        uint2 u0 = *(const uint2*)(ph + (size_t)s0 * WP + 4 * lane);
        a0.x += bf2f(u0.x & 0xffffu); a0.y += bf2f(u0.x >> 16);
        a0.z += bf2f(u0.y & 0xffffu); a0.w += bf2f(u0.y >> 16);
      }
    }
    if (lane < QUADS) {
      float4 r;
      r.x = (a0.x + a1.x) + (a2.x + a3.x);
      r.y = (a0.y + a1.y) + (a2.y + a3.y);
      r.z = (a0.z + a1.z) + (a2.z + a3.z);
      r.w = (a0.w + a1.w) + (a2.w + a3.w);
      *(float4*)(gsum + (size_t)d * WP + 4 * lane) = r;
    }
    return;
  }
  // ---- pe tile job ----
  const int b = blockIdx.x - NN;
  const int jid = b % 14;
  const int row0 = (b / 14) * 32;
  const ushort *Wh, *Wl;
  const float* bm;
  float* pe;
  int NG16 = 10, ng0, WPAD = 160, dout = 152;
  if (jid < 5) { Wh = pW1h; Wl = pW1l; bm = bm1; pe = pe1; ng0 = jid * 2; }
  else if (jid < 10) { Wh = pW2h; Wl = pW2l; bm = bm2; pe = pe2; ng0 = (jid - 5) * 2; }
  else { Wh = pW3h; Wl = pW3l; bm = bm3; pe = pe3; ng0 = (jid - 10) * 2;
         NG16 = 8; WPAD = 128; dout = 128; }
  const int rA = lane & 15, kl = (lane >> 4) * 8, colL = lane & 15;
  const int r0 = min(row0 + rA, NN - 1), r1 = min(row0 + 16 + rA, NN - 1);
  f32x4 a00 = {0.f, 0.f, 0.f, 0.f}, a01 = {0.f, 0.f, 0.f, 0.f};
  f32x4 a10 = {0.f, 0.f, 0.f, 0.f}, a11 = {0.f, 0.f, 0.f, 0.f};
#pragma unroll
  for (int kt = 0; kt < 4; ++kt) {
    size_t o0 = (size_t)r0 * 128 + kt * 32 + kl;
    size_t o1 = (size_t)r1 * 128 + kt * 32 + kl;
    bf16x8 a0h = *(const bf16x8*)(eah + o0), a0l = *(const bf16x8*)(eal + o0);
    bf16x8 a1h = *(const bf16x8*)(eah + o1), a1l = *(const bf16x8*)(eal + o1);
    size_t wb = ((size_t)(kt * NG16 + ng0) * 64 + lane) * 8;
    bf16x8 b0h = *(const bf16x8*)(Wh + wb), b0l = *(const bf16x8*)(Wl + wb);
    bf16x8 b1h = *(const bf16x8*)(Wh + wb + 512), b1l = *(const bf16x8*)(Wl + wb + 512);
    a00 = mfma3(a0h, a0l, b0h, b0l, a00);
    a01 = mfma3(a0h, a0l, b1h, b1l, a01);
    a10 = mfma3(a1h, a1l, b0h, b0l, a10);
    a11 = mfma3(a1h, a1l, b1h, b1l, a11);
  }
#pragma unroll
  for (int ms = 0; ms < 2; ++ms) {
    const f32x4 aN0 = ms ? a10 : a00;
    const f32x4 aN1 = ms ? a11 : a01;
#pragma unroll
    for (int reg = 0; reg < 4; ++reg) {
      int row = row0 + ms * 16 + (lane >> 4) * 4 + reg;
      if (row >= NN) continue;
      float dg = deg[row];
#pragma unroll
      for (int ns = 0; ns < 2; ++ns) {
        int col = (ng0 + ns) * 16 + colL;
        float v = ns ? aN1[reg] : aN0[reg];
        pe[(size_t)row * WPAD + col] = (col < dout) ? v + dg * bm[col] : 0.f;
      }
    }
  }
}

// ---------------- nm-build (light) + apply_l + proj_{l+1} ----------------
template <int KTH, int KTNM, int NGA, int NGP, bool PRED, bool A32>
__global__ __launch_bounds__(NGA * 32) void k_applyproj(
    const ushort* __restrict__ Ahi, const ushort* __restrict__ Alo,
    const float* __restrict__ Af, const float* __restrict__ gsum,
    const float* __restrict__ pe, const float* __restrict__ deg,
    const ushort* __restrict__ Wah, const ushort* __restrict__ Wal,
    const float* __restrict__ ba,
    ushort* __restrict__ Yhi, ushort* __restrict__ Ylo,
    const ushort* __restrict__ Wnh, const ushort* __restrict__ Wnl,
    ushort* __restrict__ phout, float* __restrict__ hsd,
    int dout_a, int dout_p) {
  constexpr int KTO = NGA / 2;
  constexpr int OSTR = KTO * 32;
  constexpr int SA = KTH * 32;
  constexpr int WPAD = KTNM * 32;
  constexpr int OSTR2 = NGP * 16;
  constexpr int BASE_OUT = 2 * KTNM * 1024;
  __shared__ ushort lds[BASE_OUT + 2 * KTO * 1024];
  const int tid = threadIdx.x;
  const int wid = tid >> 6, lane = tid & 63;
  const int rA = lane & 15, kl = (lane >> 4) * 8, colL = lane & 15;
  const int q = lane >> 4;
  const int row0 = blockIdx.x * 32;
  const int r0 = min(row0 + rA, NN - 1), r1 = min(row0 + 16 + rA, NN - 1);
  // ---- phase 0: elementwise nm build ----
  {
    constexpr int NT = NGA * 32;
    constexpr int TASKS = 32 * (WPAD / 4);
    for (int task = tid; task < TASKS; task += NT) {
      int row = task / (WPAD / 4);
      int k0 = (task % (WPAD / 4)) * 4;
      int grow = row0 + row;
      float4 v = {0.f, 0.f, 0.f, 0.f};
      if (grow < NN) {
        float4 g = *(const float4*)(gsum + (size_t)grow * WPAD + k0);
        float4 p = *(const float4*)(pe + (size_t)grow * WPAD + k0);
        float inv = 1.f / fmaxf(deg[grow], 1.f);
        v.x = (g.x + p.x) * inv;
        v.y = (g.y + p.y) * inv;
        v.z = (g.z + p.z) * inv;
        v.w = (g.w + p.w) * inv;
      }
      wpack4(lds, 0, KTNM, row, k0, v);
    }
  }
  __syncthreads();
  // ---- phase 1: apply ----
  if (wid < NGA / 2) {
    const int ng0 = wid * 2;
    f32x4 a00 = {0.f, 0.f, 0.f, 0.f}, a01 = {0.f, 0.f, 0.f, 0.f};
    f32x4 a10 = {0.f, 0.f, 0.f, 0.f}, a11 = {0.f, 0.f, 0.f, 0.f};
#pragma unroll
    for (int kt = 0; kt < KTH + KTNM; ++kt) {
      bf16x8 a0h, a0l, a1h, a1l;
      if (kt < KTH) {
        if constexpr (A32) {
          ld32frag(Af + (size_t)r0 * SA + kt * 32 + kl, a0h, a0l);
          ld32frag(Af + (size_t)r1 * SA + kt * 32 + kl, a1h, a1l);
        } else {
          size_t o0 = (size_t)r0 * SA + kt * 32 + kl;
          size_t o1 = (size_t)r1 * SA + kt * 32 + kl;
          a0h = *(const bf16x8*)(Ahi + o0); a0l = *(const bf16x8*)(Alo + o0);
          a1h = *(const bf16x8*)(Ahi + o1); a1l = *(const bf16x8*)(Alo + o1);
        }
      } else {
        const int rkt = kt - KTH;
        a0h = rfrag(lds, 0, KTNM, 0, rkt, lane, 0);
        a0l = rfrag(lds, 0, KTNM, 1, rkt, lane, 0);
        a1h = rfrag(lds, 0, KTNM, 0, rkt, lane, 1);
        a1l = rfrag(lds, 0, KTNM, 1, rkt, lane, 1);
      }
      size_t wb = ((size_t)(kt * NGA + ng0) * 64 + lane) * 8;
      bf16x8 b0h = *(const bf16x8*)(Wah + wb), b0l = *(const bf16x8*)(Wal + wb);
      bf16x8 b1h = *(const bf16x8*)(Wah + wb + 512), b1l = *(const bf16x8*)(Wal + wb + 512);
      a00 = mfma3(a0h, a0l, b0h, b0l, a00);
      a01 = mfma3(a0h, a0l, b1h, b1l, a01);
      a10 = mfma3(a1h, a1l, b0h, b0l, a10);
      a11 = mfma3(a1h, a1l, b1h, b1l, a11);
    }
#pragma unroll
    for (int ms = 0; ms < 2; ++ms) {
      const f32x4 aN0 = ms ? a10 : a00;
      const f32x4 aN1 = ms ? a11 : a01;
#pragma unroll
      for (int reg = 0; reg < 4; ++reg) {
        int rloc = ms * 16 + (lane >> 4) * 4 + reg;
        int row = row0 + rloc;
#pragma unroll
        for (int ns = 0; ns < 2; ++ns) {
          int col = (ng0 + ns) * 16 + colL;
          float v = ns ? aN1[reg] : aN0[reg];
          float y = (col < dout_a) ? fmaxf(v + ba[col], 0.f) : 0.f;
          ushort h = f2bf(y), l = f2bf(y - bf2f(h));
          int idx = BASE_OUT + ((col >> 5) * 4 + ((col >> 3) & 3)) * 256 + rloc * 8 + (col & 7);
          lds[idx] = h;
          lds[idx + KTO * 1024] = l;
          if constexpr (!PRED) {
            if (row < NN) {
              Yhi[(size_t)row * OSTR + col] = h;
              Ylo[(size_t)row * OSTR + col] = l;
            }
          }
        }
      }
    }
  }
  __syncthreads();
  // ---- phase 2: proj (or pred) from LDS ----
  if (wid < NGP / 2) {
    const int ng0 = wid * 2;
    f32x4 a00 = {0.f, 0.f, 0.f, 0.f}, a01 = {0.f, 0.f, 0.f, 0.f};
    f32x4 a10 = {0.f, 0.f, 0.f, 0.f}, a11 = {0.f, 0.f, 0.f, 0.f};
#pragma unroll
    for (int kt = 0; kt < KTO; ++kt) {
      int b0 = BASE_OUT + (kt * 4 + q) * 256;
      int b1 = BASE_OUT + ((KTO + kt) * 4 + q) * 256;
      bf16x8 a0h = *(const bf16x8*)(lds + b0 + rA * 8);
      bf16x8 a1h = *(const bf16x8*)(lds + b0 + (rA + 16) * 8);
      bf16x8 a0l = *(const bf16x8*)(lds + b1 + rA * 8);
      bf16x8 a1l = *(const bf16x8*)(lds + b1 + (rA + 16) * 8);
      size_t wb = ((size_t)(kt * NGP + ng0) * 64 + lane) * 8;
      bf16x8 b0h = *(const bf16x8*)(Wnh + wb), b0l = *(const bf16x8*)(Wnl + wb);
      bf16x8 b1h = *(const bf16x8*)(Wnh + wb + 512), b1l = *(const bf16x8*)(Wnl + wb + 512);
      a00 = mfma3(a0h, a0l, b0h, b0l, a00);
      a01 = mfma3(a0h, a0l, b1h, b1l, a01);
      a10 = mfma3(a1h, a1l, b0h, b0l, a10);
      a11 = mfma3(a1h, a1l, b1h, b1l, a11);
    }
#pragma unroll
    for (int ms = 0; ms < 2; ++ms) {
      const f32x4 aN0 = ms ? a10 : a00;
      const f32x4 aN1 = ms ? a11 : a01;
#pragma unroll
      for (int reg = 0; reg < 4; ++reg) {
        int row = row0 + ms * 16 + (lane >> 4) * 4 + reg;
        if (row >= NN) continue;
#pragma unroll
        for (int ns = 0; ns < 2; ++ns) {
          int col = (ng0 + ns) * 16 + colL;
          float v = ns ? aN1[reg] : aN0[reg];
          if constexpr (PRED)
            hsd[(size_t)row * 32 + col] = v;
          else
            phout[(size_t)row * OSTR2 + col] = f2bf(col < dout_p ? v : 0.f);
        }
      }
    }
  }
}

// ---------------- edge output ----------------
__global__ __launch_bounds__(256) void k_edge_out(const int* __restrict__ src,
                                                  const int* __restrict__ dst,
                                                  const float* __restrict__ hsd,
                                                  const float* __restrict__ bp,
                                                  float* __restrict__ out) {
  int i = blockIdx.x * 256 + threadIdx.x;
  if (i >= NE * 15) return;
  int e = i / 15, c = i - e * 15;
  out[i] = hsd[(size_t)src[e] * 32 + c] + hsd[(size_t)dst[e] * 32 + 15 + c] + bp[c];
}

extern "C" void kernel_launch(void* const* d_in, const int* in_sizes, int n_in,
                              void* d_out, int out_size, void* d_ws, size_t ws_size,
                              hipStream_t stream) {
  const float* nfeats = (const float*)d_in[0];
  const float* efeats = (const float*)d_in[1];
  const int* src = (const int*)d_in[2];
  const int* dst = (const int*)d_in[3];
  const float* Wm1 = (const float*)d_in[4];
  const float* bm1 = (const float*)d_in[5];
  const float* Wa1 = (const float*)d_in[6];
  const float* ba1 = (const float*)d_in[7];
  const float* Wm2 = (const float*)d_in[8];
  const float* bm2 = (const float*)d_in[9];
  const float* Wa2 = (const float*)d_in[10];
  const float* ba2 = (const float*)d_in[11];
  const float* Wm3 = (const float*)d_in[12];
  const float* bm3 = (const float*)d_in[13];
  const float* Wa3 = (const float*)d_in[14];
  const float* ba3 = (const float*)d_in[15];
  const float* Wp = (const float*)d_in[16];
  const float* bp = (const float*)d_in[17];
  float* out = (float*)d_out;

  char* base = (char*)d_ws;
  size_t woff = 0;
  auto alloc = [&](size_t bytes) -> void* {
    void* p = base + woff;
    woff += (bytes + 255) & ~(size_t)255;
    return p;
  };
  int* fill = (int*)alloc((size_t)NN * 4);
  int2* bk = (int2*)alloc((size_t)NN * MD * 8);
  float* deg = (float*)alloc((size_t)NN * 4);
  auto aplane = [&](int w) { return (ushort*)alloc((size_t)NN * w * 2); };
  ushort* eah = aplane(128); ushort* eal = aplane(128);
  ushort* h1h = aplane(160); ushort* h1l = aplane(160);
  ushort* h2h = aplane(160); ushort* h2l = aplane(160);
  ushort* ph1 = aplane(160); ushort* ph2 = aplane(160);
  float* gsum = (float*)alloc((size_t)NN * 160 * 4);
  float* pe1 = (float*)alloc((size_t)NN * 160 * 4);
  float* pe2 = (float*)alloc((size_t)NN * 160 * 4);
  float* pe3 = (float*)alloc((size_t)NN * 128 * 4);
  float* hsd = (float*)alloc((size_t)NN * 32 * 4);
  auto wpk = [&](int kt, int ng) { return (ushort*)alloc((size_t)kt * ng * 512 * 2); };
  ushort* Wm1h = wpk(8, 10);  ushort* Wm1l = wpk(8, 10);
  ushort* Wa1h = wpk(9, 10);  ushort* Wa1l = wpk(9, 10);
  ushort* Wm2h = wpk(9, 10);  ushort* Wm2l = wpk(9, 10);
  ushort* Wa2h = wpk(10, 10); ushort* Wa2l = wpk(10, 10);
  ushort* Wm3h = wpk(9, 8);   ushort* Wm3l = wpk(9, 8);
  ushort* Wa3h = wpk(9, 8);   ushort* Wa3l = wpk(9, 8);
  ushort* Wpph = wpk(4, 2);   ushort* Wppl = wpk(4, 2);

  // zero fill (tiny), then prep+bucket merged (independent block families)
  hipMemsetAsync(fill, 0, (size_t)NN * 4, stream);
  PrepArgs pa;
  pa.d[0] = {Wm1, Wm1h, Wm1l, 152, 128, 128, 128, 256, 10, 8, 0};
  pa.d[1] = {Wa1, Wa1h, Wa1l, 152, 128, 128, 152, 280, 10, 9, 0};
  pa.d[2] = {Wm2, Wm2h, Wm2l, 152, 152, 160, 128, 280, 10, 9, 0};
  pa.d[3] = {Wa2, Wa2h, Wa2l, 152, 152, 160, 152, 304, 10, 10, 0};
  pa.d[4] = {Wm3, Wm3h, Wm3l, 128, 152, 160, 128, 280, 8, 9, 0};
  pa.d[5] = {Wa3, Wa3h, Wa3l, 128, 152, 160, 128, 280, 8, 9, 0};
  pa.d[6] = {Wp, Wpph, Wppl, 32, 128, 128, 0, 256, 2, 4, 1};
  k_prepbucket<<<NBK + 7 * 40, 256, 0, stream>>>(pa, src, dst, fill, bk);

  // eagg (1 wave/node) + proj1 tiles
  k_eaggproj<<<NN + 5 * MTB, 64, 0, stream>>>(
      efeats, bk, fill, nfeats, Wm1h, Wm1l, eah, eal, deg, ph1);

  const ushort* pW1h = Wm1h + (size_t)4 * 10 * 512;
  const ushort* pW1l = Wm1l + (size_t)4 * 10 * 512;
  const ushort* pW2h = Wm2h + (size_t)5 * 10 * 512;
  const ushort* pW2l = Wm2l + (size_t)5 * 10 * 512;
  const ushort* pW3h = Wm3h + (size_t)5 * 8 * 512;
  const ushort* pW3l = Wm3l + (size_t)5 * 8 * 512;

  // layer 1: gather(ph1) + pe1/pe2/pe3 tiles (one dispatch) -> apply1+proj2
  k_gath<160, true><<<NN + 14 * MTB, 64, 0, stream>>>(
      ph1, bk, fill, gsum, eah, eal, pW1h, pW1l, pW2h, pW2l, pW3h, pW3l,
      bm1, bm2, bm3, deg, pe1, pe2, pe3);
  k_applyproj<4, 5, 10, 10, false, true><<<MTB, 320, 0, stream>>>(
      nullptr, nullptr, nfeats, gsum, pe1, deg, Wa1h, Wa1l, ba1,
      h1h, h1l, Wm2h, Wm2l, ph2, nullptr, 152, 152);
  // layer 2
  k_gath<160, false><<<NN, 64, 0, stream>>>(
      ph2, bk, fill, gsum, nullptr, nullptr, nullptr, nullptr, nullptr, nullptr,
      nullptr, nullptr, nullptr, nullptr, nullptr, deg, nullptr, nullptr, nullptr);
  k_applyproj<5, 5, 10, 8, false, false><<<MTB, 320, 0, stream>>>(
      h1h, h1l, nullptr, gsum, pe2, deg, Wa2h, Wa2l, ba2,
      h2h, h2l, Wm3h, Wm3l, ph1, nullptr, 152, 128);
  // layer 3: apply3 + edge predictor (h3 never hits global)
  k_gath<128, false><<<NN, 64, 0, stream>>>(
      ph1, bk, fill, gsum, nullptr, nullptr, nullptr, nullptr, nullptr, nullptr,
      nullptr, nullptr, nullptr, nullptr, nullptr, deg, nullptr, nullptr, nullptr);
  k_applyproj<5, 4, 8, 2, true, false><<<MTB, 256, 0, stream>>>(
      h2h, h2l, nullptr, gsum, pe3, deg, Wa3h, Wa3l, ba3,
      nullptr, nullptr, Wpph, Wppl, nullptr, hsd, 128, 32);

  k_edge_out<<<cdiv(NE * 15, 256), 256, 0, stream>>>(src, dst, hsd, bp, out);
}

// Round 14
// 201.462 us; speedup vs baseline: 1.0156x; 1.0156x over previous
//
#include <hip/hip_runtime.h>
#include <hip/hip_bf16.h>
#include <cstdint>

// GraphSAGE 3-layer + edge predictor (10 dispatches) — R12 configuration
// (best measured: 201.7 us).
//   segsum(concat(h[src],e)@Wm.T+bm,dst) = segsum(ph[src]) + pe
//     ph = h@Wmh.T (commutes past segsum), pe = eagg@Wme.T + deg*bm
//   eagg/deg layer-independent. ph bf16-hi (3.2MB, L2-resident gather table).
// Dispatch-merge rules (R4/R8/R10/R11/R13): 1 node = 1 wave = 1 block for
// eagg/gather; never move wide parallel work into the per-layer serial path;
// independent tile jobs may ride a latency-bound dispatch as extra blocks.
// proj1 rides eagg; pe1/2/3 ride gather-1; fill zeroing rides prep.
// MFMA 16x16x32 bf16 hi/lo split (3 MFMA, err ~2^-17); A and W packed with
// the SAME (lane,elem)->k map.

static inline int cdiv(int a, int b) { return (a + b - 1) / b; }

#define NN 10000
#define NE 320000
#define MTB 313  // cdiv(NN,32)
#define MD 192   // bucket capacity per node

typedef __attribute__((ext_vector_type(8))) short bf16x8;
typedef __attribute__((ext_vector_type(4))) float f32x4;

__device__ __forceinline__ ushort f2bf(float x) {
  union { float f; unsigned u; } c; c.f = x;
  unsigned r = c.u + 0x7FFFu + ((c.u >> 16) & 1u);
  return (ushort)(r >> 16);
}
__device__ __forceinline__ float bf2f(unsigned h) {
  union { unsigned u; float f; } c; c.u = h << 16;
  return c.f;
}
__device__ __forceinline__ f32x4 mfma3(bf16x8 ah, bf16x8 al, bf16x8 bh, bf16x8 bl,
                                       f32x4 acc) {
  acc = __builtin_amdgcn_mfma_f32_16x16x32_bf16(ah, bh, acc, 0, 0, 0);
  acc = __builtin_amdgcn_mfma_f32_16x16x32_bf16(al, bh, acc, 0, 0, 0);
  acc = __builtin_amdgcn_mfma_f32_16x16x32_bf16(ah, bl, acc, 0, 0, 0);
  return acc;
}
// load 8 consecutive fp32 -> hi/lo bf16 fragments
__device__ __forceinline__ void ld32frag(const float* p, bf16x8& h, bf16x8& l) {
  float4 x0 = *(const float4*)p;
  float4 x1 = *(const float4*)(p + 4);
  float v[8] = {x0.x, x0.y, x0.z, x0.w, x1.x, x1.y, x1.z, x1.w};
#pragma unroll
  for (int j = 0; j < 8; ++j) {
    ushort hh = f2bf(v[j]);
    h[j] = (short)hh;
    l[j] = (short)f2bf(v[j] - bf2f(hh));
  }
}
// packed-A LDS tile: [plane][kt][q][row32][8] bf16; float4-wide write
__device__ __forceinline__ void wpack4(ushort* lds, int base, int KT, int row,
                                       int k0, float4 v) {
  int idx0 = base + ((k0 >> 5) * 4 + ((k0 >> 3) & 3)) * 256 + row * 8 + (k0 & 7);
  int idx1 = idx0 + KT * 1024;
  ushort h0 = f2bf(v.x), h1 = f2bf(v.y), h2 = f2bf(v.z), h3 = f2bf(v.w);
  uint2 uh, ul;
  uh.x = (unsigned)h0 | ((unsigned)h1 << 16);
  uh.y = (unsigned)h2 | ((unsigned)h3 << 16);
  ushort l0 = f2bf(v.x - bf2f(h0)), l1 = f2bf(v.y - bf2f(h1));
  ushort l2 = f2bf(v.z - bf2f(h2)), l3 = f2bf(v.w - bf2f(h3));
  ul.x = (unsigned)l0 | ((unsigned)l1 << 16);
  ul.y = (unsigned)l2 | ((unsigned)l3 << 16);
  *reinterpret_cast<uint2*>(&lds[idx0]) = uh;
  *reinterpret_cast<uint2*>(&lds[idx1]) = ul;
}
__device__ __forceinline__ bf16x8 rfrag(const ushort* lds, int base, int KT,
                                        int plane, int kt, int lane, int mh) {
  int idx = base + ((plane * KT + kt) * 4 + (lane >> 4)) * 256 +
            ((lane & 15) + 16 * mh) * 8;
  return *reinterpret_cast<const bf16x8*>(&lds[idx]);
}

// ---------------- bucket build ----------------
__global__ __launch_bounds__(256) void k_bucket(const int* __restrict__ src,
                                                const int* __restrict__ dst,
                                                int* __restrict__ fill,
                                                int2* __restrict__ bk) {
  int e = blockIdx.x * 256 + threadIdx.x;
  if (e < NE) {
    int d = dst[e];
    int pos = atomicAdd(&fill[d], 1);
    if (pos < MD) bk[d * MD + pos] = make_int2(e, src[e]);
  }
}

// ---------------- prep: W packs (y<7) + fill zero (y==7) ----------------
struct WDesc {
  const float* W; ushort* hi; ushort* lo;
  int dout, KA, KApad, KB, Korig, NG16, KT, pred;
};
struct PrepArgs {
  WDesc d[7];
  int* fill;
};

__global__ __launch_bounds__(256) void k_prep(PrepArgs P) {
  const int y = blockIdx.y;
  if (y == 7) {
    int i = blockIdx.x * 256 + threadIdx.x;
    if (i < NN) P.fill[i] = 0;
    return;
  }
  const WDesc d = P.d[y];
  int tid = blockIdx.x * 256 + threadIdx.x;
  if (tid >= d.KT * d.NG16 * 64) return;
  int lane = tid & 63;
  int g = (tid >> 6) % d.NG16;
  int t = (tid >> 6) / d.NG16;
  int col = g * 16 + (lane & 15);
  int kbase = t * 32 + ((lane >> 4) * 8);
  size_t o = (size_t)tid * 8;
#pragma unroll
  for (int j = 0; j < 8; ++j) {
    int kk = kbase + j;
    float w = 0.f;
    if (!d.pred) {
      if (col < d.dout) {
        if (kk < d.KApad) { if (kk < d.KA) w = d.W[(size_t)col * d.Korig + kk]; }
        else { int kb = kk - d.KApad; if (kb < d.KB) w = d.W[(size_t)col * d.Korig + d.KA + kb]; }
      }
    } else {
      if (col < 15) w = d.W[(size_t)col * 256 + kk];
      else if (col < 30) w = d.W[(size_t)(col - 15) * 256 + 128 + kk];
    }
    ushort h = f2bf(w);
    d.hi[o + j] = h;
    d.lo[o + j] = f2bf(w - bf2f(h));
  }
}

// ---------------- eagg (1 wave/node) + proj1 tiles (extra blocks) ----------
__global__ __launch_bounds__(64) void k_eaggproj(
    const float* __restrict__ efeats, const int2* __restrict__ bk,
    const int* __restrict__ fill, const float* __restrict__ nfeats,
    const ushort* __restrict__ Wm1h, const ushort* __restrict__ Wm1l,
    ushort* __restrict__ ehi, ushort* __restrict__ elo,
    float* __restrict__ deg, ushort* __restrict__ ph1) {
  const int lane = threadIdx.x;
  if (blockIdx.x < NN) {
    const int d = blockIdx.x;
    const int half = lane >> 5, cl = lane & 31;
    const int cntd = fill[d];
    const int n = min(cntd, MD);
    const int s = d * MD, t = s + n;
    float4 acc[8];
#pragma unroll
    for (int u = 0; u < 8; ++u) acc[u] = make_float4(0.f, 0.f, 0.f, 0.f);
    int j = s;
    for (; j + 15 < t; j += 16) {
#pragma unroll
      for (int u = 0; u < 8; ++u) {
        int e0 = bk[j + 2 * u + half].x;
        float4 v = *(const float4*)(efeats + (size_t)e0 * 128 + cl * 4);
        acc[u].x += v.x; acc[u].y += v.y; acc[u].z += v.z; acc[u].w += v.w;
      }
    }
    for (; j + 1 < t; j += 2) {
      int e0 = bk[j + half].x;
      float4 v = *(const float4*)(efeats + (size_t)e0 * 128 + cl * 4);
      acc[0].x += v.x; acc[0].y += v.y; acc[0].z += v.z; acc[0].w += v.w;
    }
    if (j < t && half == 0) {
      int e0 = bk[j].x;
      float4 v = *(const float4*)(efeats + (size_t)e0 * 128 + cl * 4);
      acc[0].x += v.x; acc[0].y += v.y; acc[0].z += v.z; acc[0].w += v.w;
    }
#pragma unroll
    for (int u = 4; u > 0; u >>= 1)
#pragma unroll
      for (int w = 0; w < u; ++w) {
        acc[w].x += acc[w + u].x; acc[w].y += acc[w + u].y;
        acc[w].z += acc[w + u].z; acc[w].w += acc[w + u].w;
      }
    float4 sm = acc[0];
    sm.x += __shfl_xor(sm.x, 32);
    sm.y += __shfl_xor(sm.y, 32);
    sm.z += __shfl_xor(sm.z, 32);
    sm.w += __shfl_xor(sm.w, 32);
    if (lane < 32) {
      size_t o = (size_t)d * 128 + cl * 4;
      ushort h0 = f2bf(sm.x), h1 = f2bf(sm.y), h2 = f2bf(sm.z), h3 = f2bf(sm.w);
      uint2 uh, ul;
      uh.x = (unsigned)h0 | ((unsigned)h1 << 16);
      uh.y = (unsigned)h2 | ((unsigned)h3 << 16);
      ul.x = (unsigned)f2bf(sm.x - bf2f(h0)) | ((unsigned)f2bf(sm.y - bf2f(h1)) << 16);
      ul.y = (unsigned)f2bf(sm.z - bf2f(h2)) | ((unsigned)f2bf(sm.w - bf2f(h3)) << 16);
      *(uint2*)(ehi + o) = uh;
      *(uint2*)(elo + o) = ul;
    }
    if (lane == 0) deg[d] = (float)cntd;
    return;
  }
  // ---- proj1 tile: ph1 = nfeats @ Wm1(h-part), bf16-hi ----
  const int p = blockIdx.x - NN;
  const int ng0 = (p % 5) * 2;
  const int row0 = (p / 5) * 32;
  const int rA = lane & 15, kl = (lane >> 4) * 8, colL = lane & 15;
  const int r0 = min(row0 + rA, NN - 1), r1 = min(row0 + 16 + rA, NN - 1);
  f32x4 a00 = {0.f, 0.f, 0.f, 0.f}, a01 = {0.f, 0.f, 0.f, 0.f};
  f32x4 a10 = {0.f, 0.f, 0.f, 0.f}, a11 = {0.f, 0.f, 0.f, 0.f};
#pragma unroll
  for (int kt = 0; kt < 4; ++kt) {
    bf16x8 a0h, a0l, a1h, a1l;
    ld32frag(nfeats + (size_t)r0 * 128 + kt * 32 + kl, a0h, a0l);
    ld32frag(nfeats + (size_t)r1 * 128 + kt * 32 + kl, a1h, a1l);
    size_t wb = ((size_t)(kt * 10 + ng0) * 64 + lane) * 8;
    bf16x8 b0h = *(const bf16x8*)(Wm1h + wb), b0l = *(const bf16x8*)(Wm1l + wb);
    bf16x8 b1h = *(const bf16x8*)(Wm1h + wb + 512), b1l = *(const bf16x8*)(Wm1l + wb + 512);
    a00 = mfma3(a0h, a0l, b0h, b0l, a00);
    a01 = mfma3(a0h, a0l, b1h, b1l, a01);
    a10 = mfma3(a1h, a1l, b0h, b0l, a10);
    a11 = mfma3(a1h, a1l, b1h, b1l, a11);
  }
#pragma unroll
  for (int ms = 0; ms < 2; ++ms) {
    const f32x4 aN0 = ms ? a10 : a00;
    const f32x4 aN1 = ms ? a11 : a01;
#pragma unroll
    for (int reg = 0; reg < 4; ++reg) {
      int row = row0 + ms * 16 + (lane >> 4) * 4 + reg;
      if (row >= NN) continue;
#pragma unroll
      for (int ns = 0; ns < 2; ++ns) {
        int col = (ng0 + ns) * 16 + colL;
        float v = ns ? aN1[reg] : aN0[reg];
        ph1[(size_t)row * 160 + col] = f2bf(col < 152 ? v : 0.f);
      }
    }
  }
}

// ---------------- gather (pure f32 sum) + optional pe tiles ----------------
template <int WP, bool PE>
__global__ __launch_bounds__(64) void k_gath(
    const ushort* __restrict__ ph, const int2* __restrict__ bk,
    const int* __restrict__ fill, float* __restrict__ gsum,
    const ushort* __restrict__ eah, const ushort* __restrict__ eal,
    const ushort* __restrict__ pW1h, const ushort* __restrict__ pW1l,
    const ushort* __restrict__ pW2h, const ushort* __restrict__ pW2l,
    const ushort* __restrict__ pW3h, const ushort* __restrict__ pW3l,
    const float* __restrict__ bm1, const float* __restrict__ bm2,
    const float* __restrict__ bm3, const float* __restrict__ deg,
    float* __restrict__ pe1, float* __restrict__ pe2, float* __restrict__ pe3) {
  const int lane = threadIdx.x;
  if (!PE || blockIdx.x < NN) {
    constexpr int QUADS = WP / 4;  // 40 or 32 active lanes
    const int d = blockIdx.x;
    const int n = min(fill[d], MD);
    const int s = d * MD, t = s + n;
    float4 a0 = {0.f, 0.f, 0.f, 0.f}, a1 = a0, a2 = a0, a3 = a0;
    int j = s;
    for (; j + 3 < t; j += 4) {
      int s0 = bk[j].y, s1 = bk[j + 1].y, s2 = bk[j + 2].y, s3 = bk[j + 3].y;
      if (lane < QUADS) {
        uint2 u0 = *(const uint2*)(ph + (size_t)s0 * WP + 4 * lane);
        uint2 u1 = *(const uint2*)(ph + (size_t)s1 * WP + 4 * lane);
        uint2 u2 = *(const uint2*)(ph + (size_t)s2 * WP + 4 * lane);
        uint2 u3 = *(const uint2*)(ph + (size_t)s3 * WP + 4 * lane);
        a0.x += bf2f(u0.x & 0xffffu); a0.y += bf2f(u0.x >> 16);
        a0.z += bf2f(u0.y & 0xffffu); a0.w += bf2f(u0.y >> 16);
        a1.x += bf2f(u1.x & 0xffffu); a1.y += bf2f(u1.x >> 16);
        a1.z += bf2f(u1.y & 0xffffu); a1.w += bf2f(u1.y >> 16);
        a2.x += bf2f(u2.x & 0xffffu); a2.y += bf2f(u2.x >> 16);
        a2.z += bf2f(u2.y & 0xffffu); a2.w += bf2f(u2.y >> 16);
        a3.x += bf2f(u3.x & 0xffffu); a3.y += bf2f(u3.x >> 16);
        a3.z += bf2f(u3.y & 0xffffu); a3.w += bf2f(u3.y >> 16);
      }
    }
    for (; j < t; ++j) {
      int s0 = bk[j].y;
      if (lane < QUADS) {
        uint2 u0 = *(const uint2*)(ph + (size_t)s0 * WP + 4 * lane);
        a0.x += bf2f(u0.x & 0xffffu); a0.y += bf2f(u0.x >> 16);
        a0.z += bf2f(u0.y & 0xffffu); a0.w += bf2f(u0.y >> 16);
      }
    }
    if (lane < QUADS) {
      float4 r;
      r.x = (a0.x + a1.x) + (a2.x + a3.x);
      r.y = (a0.y + a1.y) + (a2.y + a3.y);
      r.z = (a0.z + a1.z) + (a2.z + a3.z);
      r.w = (a0.w + a1.w) + (a2.w + a3.w);
      *(float4*)(gsum + (size_t)d * WP + 4 * lane) = r;
    }
    return;
  }
  // ---- pe tile job ----
  const int b = blockIdx.x - NN;
  const int jid = b % 14;
  const int row0 = (b / 14) * 32;
  const ushort *Wh, *Wl;
  const float* bm;
  float* pe;
  int NG16 = 10, ng0, WPAD = 160, dout = 152;
  if (jid < 5) { Wh = pW1h; Wl = pW1l; bm = bm1; pe = pe1; ng0 = jid * 2; }
  else if (jid < 10) { Wh = pW2h; Wl = pW2l; bm = bm2; pe = pe2; ng0 = (jid - 5) * 2; }
  else { Wh = pW3h; Wl = pW3l; bm = bm3; pe = pe3; ng0 = (jid - 10) * 2;
         NG16 = 8; WPAD = 128; dout = 128; }
  const int rA = lane & 15, kl = (lane >> 4) * 8, colL = lane & 15;
  const int r0 = min(row0 + rA, NN - 1), r1 = min(row0 + 16 + rA, NN - 1);
  f32x4 a00 = {0.f, 0.f, 0.f, 0.f}, a01 = {0.f, 0.f, 0.f, 0.f};
  f32x4 a10 = {0.f, 0.f, 0.f, 0.f}, a11 = {0.f, 0.f, 0.f, 0.f};
#pragma unroll
  for (int kt = 0; kt < 4; ++kt) {
    size_t o0 = (size_t)r0 * 128 + kt * 32 + kl;
    size_t o1 = (size_t)r1 * 128 + kt * 32 + kl;
    bf16x8 a0h = *(const bf16x8*)(eah + o0), a0l = *(const bf16x8*)(eal + o0);
    bf16x8 a1h = *(const bf16x8*)(eah + o1), a1l = *(const bf16x8*)(eal + o1);
    size_t wb = ((size_t)(kt * NG16 + ng0) * 64 + lane) * 8;
    bf16x8 b0h = *(const bf16x8*)(Wh + wb), b0l = *(const bf16x8*)(Wl + wb);
    bf16x8 b1h = *(const bf16x8*)(Wh + wb + 512), b1l = *(const bf16x8*)(Wl + wb + 512);
    a00 = mfma3(a0h, a0l, b0h, b0l, a00);
    a01 = mfma3(a0h, a0l, b1h, b1l, a01);
    a10 = mfma3(a1h, a1l, b0h, b0l, a10);
    a11 = mfma3(a1h, a1l, b1h, b1l, a11);
  }
#pragma unroll
  for (int ms = 0; ms < 2; ++ms) {
    const f32x4 aN0 = ms ? a10 : a00;
    const f32x4 aN1 = ms ? a11 : a01;
#pragma unroll
    for (int reg = 0; reg < 4; ++reg) {
      int row = row0 + ms * 16 + (lane >> 4) * 4 + reg;
      if (row >= NN) continue;
      float dg = deg[row];
#pragma unroll
      for (int ns = 0; ns < 2; ++ns) {
        int col = (ng0 + ns) * 16 + colL;
        float v = ns ? aN1[reg] : aN0[reg];
        pe[(size_t)row * WPAD + col] = (col < dout) ? v + dg * bm[col] : 0.f;
      }
    }
  }
}

// ---------------- nm-build (light) + apply_l + proj_{l+1} ----------------
template <int KTH, int KTNM, int NGA, int NGP, bool PRED, bool A32>
__global__ __launch_bounds__(NGA * 32) void k_applyproj(
    const ushort* __restrict__ Ahi, const ushort* __restrict__ Alo,
    const float* __restrict__ Af, const float* __restrict__ gsum,
    const float* __restrict__ pe, const float* __restrict__ deg,
    const ushort* __restrict__ Wah, const ushort* __restrict__ Wal,
    const float* __restrict__ ba,
    ushort* __restrict__ Yhi, ushort* __restrict__ Ylo,
    const ushort* __restrict__ Wnh, const ushort* __restrict__ Wnl,
    ushort* __restrict__ phout, float* __restrict__ hsd,
    int dout_a, int dout_p) {
  constexpr int KTO = NGA / 2;
  constexpr int OSTR = KTO * 32;
  constexpr int SA = KTH * 32;
  constexpr int WPAD = KTNM * 32;
  constexpr int OSTR2 = NGP * 16;
  constexpr int BASE_OUT = 2 * KTNM * 1024;
  __shared__ ushort lds[BASE_OUT + 2 * KTO * 1024];
  const int tid = threadIdx.x;
  const int wid = tid >> 6, lane = tid & 63;
  const int rA = lane & 15, kl = (lane >> 4) * 8, colL = lane & 15;
  const int q = lane >> 4;
  const int row0 = blockIdx.x * 32;
  const int r0 = min(row0 + rA, NN - 1), r1 = min(row0 + 16 + rA, NN - 1);
  // ---- phase 0: elementwise nm build ----
  {
    constexpr int NT = NGA * 32;
    constexpr int TASKS = 32 * (WPAD / 4);
    for (int task = tid; task < TASKS; task += NT) {
      int row = task / (WPAD / 4);
      int k0 = (task % (WPAD / 4)) * 4;
      int grow = row0 + row;
      float4 v = {0.f, 0.f, 0.f, 0.f};
      if (grow < NN) {
        float4 g = *(const float4*)(gsum + (size_t)grow * WPAD + k0);
        float4 p = *(const float4*)(pe + (size_t)grow * WPAD + k0);
        float inv = 1.f / fmaxf(deg[grow], 1.f);
        v.x = (g.x + p.x) * inv;
        v.y = (g.y + p.y) * inv;
        v.z = (g.z + p.z) * inv;
        v.w = (g.w + p.w) * inv;
      }
      wpack4(lds, 0, KTNM, row, k0, v);
    }
  }
  __syncthreads();
  // ---- phase 1: apply ----
  if (wid < NGA / 2) {
    const int ng0 = wid * 2;
    f32x4 a00 = {0.f, 0.f, 0.f, 0.f}, a01 = {0.f, 0.f, 0.f, 0.f};
    f32x4 a10 = {0.f, 0.f, 0.f, 0.f}, a11 = {0.f, 0.f, 0.f, 0.f};
#pragma unroll
    for (int kt = 0; kt < KTH + KTNM; ++kt) {
      bf16x8 a0h, a0l, a1h, a1l;
      if (kt < KTH) {
        if constexpr (A32) {
          ld32frag(Af + (size_t)r0 * SA + kt * 32 + kl, a0h, a0l);
          ld32frag(Af + (size_t)r1 * SA + kt * 32 + kl, a1h, a1l);
        } else {
          size_t o0 = (size_t)r0 * SA + kt * 32 + kl;
          size_t o1 = (size_t)r1 * SA + kt * 32 + kl;
          a0h = *(const bf16x8*)(Ahi + o0); a0l = *(const bf16x8*)(Alo + o0);
          a1h = *(const bf16x8*)(Ahi + o1); a1l = *(const bf16x8*)(Alo + o1);
        }
      } else {
        const int rkt = kt - KTH;
        a0h = rfrag(lds, 0, KTNM, 0, rkt, lane, 0);
        a0l = rfrag(lds, 0, KTNM, 1, rkt, lane, 0);
        a1h = rfrag(lds, 0, KTNM, 0, rkt, lane, 1);
        a1l = rfrag(lds, 0, KTNM, 1, rkt, lane, 1);
      }
      size_t wb = ((size_t)(kt * NGA + ng0) * 64 + lane) * 8;
      bf16x8 b0h = *(const bf16x8*)(Wah + wb), b0l = *(const bf16x8*)(Wal + wb);
      bf16x8 b1h = *(const bf16x8*)(Wah + wb + 512), b1l = *(const bf16x8*)(Wal + wb + 512);
      a00 = mfma3(a0h, a0l, b0h, b0l, a00);
      a01 = mfma3(a0h, a0l, b1h, b1l, a01);
      a10 = mfma3(a1h, a1l, b0h, b0l, a10);
      a11 = mfma3(a1h, a1l, b1h, b1l, a11);
    }
#pragma unroll
    for (int ms = 0; ms < 2; ++ms) {
      const f32x4 aN0 = ms ? a10 : a00;
      const f32x4 aN1 = ms ? a11 : a01;
#pragma unroll
      for (int reg = 0; reg < 4; ++reg) {
        int rloc = ms * 16 + (lane >> 4) * 4 + reg;
        int row = row0 + rloc;
#pragma unroll
        for (int ns = 0; ns < 2; ++ns) {
          int col = (ng0 + ns) * 16 + colL;
          float v = ns ? aN1[reg] : aN0[reg];
          float y = (col < dout_a) ? fmaxf(v + ba[col], 0.f) : 0.f;
          ushort h = f2bf(y), l = f2bf(y - bf2f(h));
          int idx = BASE_OUT + ((col >> 5) * 4 + ((col >> 3) & 3)) * 256 + rloc * 8 + (col & 7);
          lds[idx] = h;
          lds[idx + KTO * 1024] = l;
          if constexpr (!PRED) {
            if (row < NN) {
              Yhi[(size_t)row * OSTR + col] = h;
              Ylo[(size_t)row * OSTR + col] = l;
            }
          }
        }
      }
    }
  }
  __syncthreads();
  // ---- phase 2: proj (or pred) from LDS ----
  if (wid < NGP / 2) {
    const int ng0 = wid * 2;
    f32x4 a00 = {0.f, 0.f, 0.f, 0.f}, a01 = {0.f, 0.f, 0.f, 0.f};
    f32x4 a10 = {0.f, 0.f, 0.f, 0.f}, a11 = {0.f, 0.f, 0.f, 0.f};
#pragma unroll
    for (int kt = 0; kt < KTO; ++kt) {
      int b0 = BASE_OUT + (kt * 4 + q) * 256;
      int b1 = BASE_OUT + ((KTO + kt) * 4 + q) * 256;
      bf16x8 a0h = *(const bf16x8*)(lds + b0 + rA * 8);
      bf16x8 a1h = *(const bf16x8*)(lds + b0 + (rA + 16) * 8);
      bf16x8 a0l = *(const bf16x8*)(lds + b1 + rA * 8);
      bf16x8 a1l = *(const bf16x8*)(lds + b1 + (rA + 16) * 8);
      size_t wb = ((size_t)(kt * NGP + ng0) * 64 + lane) * 8;
      bf16x8 b0h = *(const bf16x8*)(Wnh + wb), b0l = *(const bf16x8*)(Wnl + wb);
      bf16x8 b1h = *(const bf16x8*)(Wnh + wb + 512), b1l = *(const bf16x8*)(Wnl + wb + 512);
      a00 = mfma3(a0h, a0l, b0h, b0l, a00);
      a01 = mfma3(a0h, a0l, b1h, b1l, a01);
      a10 = mfma3(a1h, a1l, b0h, b0l, a10);
      a11 = mfma3(a1h, a1l, b1h, b1l, a11);
    }
#pragma unroll
    for (int ms = 0; ms < 2; ++ms) {
      const f32x4 aN0 = ms ? a10 : a00;
      const f32x4 aN1 = ms ? a11 : a01;
#pragma unroll
      for (int reg = 0; reg < 4; ++reg) {
        int row = row0 + ms * 16 + (lane >> 4) * 4 + reg;
        if (row >= NN) continue;
#pragma unroll
        for (int ns = 0; ns < 2; ++ns) {
          int col = (ng0 + ns) * 16 + colL;
          float v = ns ? aN1[reg] : aN0[reg];
          if constexpr (PRED)
            hsd[(size_t)row * 32 + col] = v;
          else
            phout[(size_t)row * OSTR2 + col] = f2bf(col < dout_p ? v : 0.f);
        }
      }
    }
  }
}

// ---------------- edge output ----------------
__global__ __launch_bounds__(256) void k_edge_out(const int* __restrict__ src,
                                                  const int* __restrict__ dst,
                                                  const float* __restrict__ hsd,
                                                  const float* __restrict__ bp,
                                                  float* __restrict__ out) {
  int i = blockIdx.x * 256 + threadIdx.x;
  if (i >= NE * 15) return;
  int e = i / 15, c = i - e * 15;
  out[i] = hsd[(size_t)src[e] * 32 + c] + hsd[(size_t)dst[e] * 32 + 15 + c] + bp[c];
}

extern "C" void kernel_launch(void* const* d_in, const int* in_sizes, int n_in,
                              void* d_out, int out_size, void* d_ws, size_t ws_size,
                              hipStream_t stream) {
  const float* nfeats = (const float*)d_in[0];
  const float* efeats = (const float*)d_in[1];
  const int* src = (const int*)d_in[2];
  const int* dst = (const int*)d_in[3];
  const float* Wm1 = (const float*)d_in[4];
  const float* bm1 = (const float*)d_in[5];
  const float* Wa1 = (const float*)d_in[6];
  const float* ba1 = (const float*)d_in[7];
  const float* Wm2 = (const float*)d_in[8];
  const float* bm2 = (const float*)d_in[9];
  const float* Wa2 = (const float*)d_in[10];
  const float* ba2 = (const float*)d_in[11];
  const float* Wm3 = (const float*)d_in[12];
  const float* bm3 = (const float*)d_in[13];
  const float* Wa3 = (const float*)d_in[14];
  const float* ba3 = (const float*)d_in[15];
  const float* Wp = (const float*)d_in[16];
  const float* bp = (const float*)d_in[17];
  float* out = (float*)d_out;

  char* base = (char*)d_ws;
  size_t woff = 0;
  auto alloc = [&](size_t bytes) -> void* {
    void* p = base + woff;
    woff += (bytes + 255) & ~(size_t)255;
    return p;
  };
  int* fill = (int*)alloc((size_t)NN * 4);
  int2* bk = (int2*)alloc((size_t)NN * MD * 8);
  float* deg = (float*)alloc((size_t)NN * 4);
  auto aplane = [&](int w) { return (ushort*)alloc((size_t)NN * w * 2); };
  ushort* eah = aplane(128); ushort* eal = aplane(128);
  ushort* h1h = aplane(160); ushort* h1l = aplane(160);
  ushort* h2h = aplane(160); ushort* h2l = aplane(160);
  ushort* ph1 = aplane(160); ushort* ph2 = aplane(160);
  float* gsum = (float*)alloc((size_t)NN * 160 * 4);
  float* pe1 = (float*)alloc((size_t)NN * 160 * 4);
  float* pe2 = (float*)alloc((size_t)NN * 160 * 4);
  float* pe3 = (float*)alloc((size_t)NN * 128 * 4);
  float* hsd = (float*)alloc((size_t)NN * 32 * 4);
  auto wpk = [&](int kt, int ng) { return (ushort*)alloc((size_t)kt * ng * 512 * 2); };
  ushort* Wm1h = wpk(8, 10);  ushort* Wm1l = wpk(8, 10);
  ushort* Wa1h = wpk(9, 10);  ushort* Wa1l = wpk(9, 10);
  ushort* Wm2h = wpk(9, 10);  ushort* Wm2l = wpk(9, 10);
  ushort* Wa2h = wpk(10, 10); ushort* Wa2l = wpk(10, 10);
  ushort* Wm3h = wpk(9, 8);   ushort* Wm3l = wpk(9, 8);
  ushort* Wa3h = wpk(9, 8);   ushort* Wa3l = wpk(9, 8);
  ushort* Wpph = wpk(4, 2);   ushort* Wppl = wpk(4, 2);

  // prep: 7 weight packs + fill zeroing (one dispatch)
  PrepArgs pa;
  pa.d[0] = {Wm1, Wm1h, Wm1l, 152, 128, 128, 128, 256, 10, 8, 0};
  pa.d[1] = {Wa1, Wa1h, Wa1l, 152, 128, 128, 152, 280, 10, 9, 0};
  pa.d[2] = {Wm2, Wm2h, Wm2l, 152, 152, 160, 128, 280, 10, 9, 0};
  pa.d[3] = {Wa2, Wa2h, Wa2l, 152, 152, 160, 152, 304, 10, 10, 0};
  pa.d[4] = {Wm3, Wm3h, Wm3l, 128, 152, 160, 128, 280, 8, 9, 0};
  pa.d[5] = {Wa3, Wa3h, Wa3l, 128, 152, 160, 128, 280, 8, 9, 0};
  pa.d[6] = {Wp, Wpph, Wppl, 32, 128, 128, 0, 256, 2, 4, 1};
  pa.fill = fill;
  k_prep<<<dim3(40, 8), 256, 0, stream>>>(pa);

  // bucket build
  k_bucket<<<cdiv(NE, 256), 256, 0, stream>>>(src, dst, fill, bk);

  // eagg (1 wave/node) + proj1 tiles
  k_eaggproj<<<NN + 5 * MTB, 64, 0, stream>>>(
      efeats, bk, fill, nfeats, Wm1h, Wm1l, eah, eal, deg, ph1);

  const ushort* pW1h = Wm1h + (size_t)4 * 10 * 512;
  const ushort* pW1l = Wm1l + (size_t)4 * 10 * 512;
  const ushort* pW2h = Wm2h + (size_t)5 * 10 * 512;
  const ushort* pW2l = Wm2l + (size_t)5 * 10 * 512;
  const ushort* pW3h = Wm3h + (size_t)5 * 8 * 512;
  const ushort* pW3l = Wm3l + (size_t)5 * 8 * 512;

  // layer 1: gather(ph1) + pe1/pe2/pe3 tiles (one dispatch) -> apply1+proj2
  k_gath<160, true><<<NN + 14 * MTB, 64, 0, stream>>>(
      ph1, bk, fill, gsum, eah, eal, pW1h, pW1l, pW2h, pW2l, pW3h, pW3l,
      bm1, bm2, bm3, deg, pe1, pe2, pe3);
  k_applyproj<4, 5, 10, 10, false, true><<<MTB, 320, 0, stream>>>(
      nullptr, nullptr, nfeats, gsum, pe1, deg, Wa1h, Wa1l, ba1,
      h1h, h1l, Wm2h, Wm2l, ph2, nullptr, 152, 152);
  // layer 2
  k_gath<160, false><<<NN, 64, 0, stream>>>(
      ph2, bk, fill, gsum, nullptr, nullptr, nullptr, nullptr, nullptr, nullptr,
      nullptr, nullptr, nullptr, nullptr, nullptr, deg, nullptr, nullptr, nullptr);
  k_applyproj<5, 5, 10, 8, false, false><<<MTB, 320, 0, stream>>>(
      h1h, h1l, nullptr, gsum, pe2, deg, Wa2h, Wa2l, ba2,
      h2h, h2l, Wm3h, Wm3l, ph1, nullptr, 152, 128);
  // layer 3: apply3 + edge predictor (h3 never hits global)
  k_gath<128, false><<<NN, 64, 0, stream>>>(
      ph1, bk, fill, gsum, nullptr, nullptr, nullptr, nullptr, nullptr, nullptr,
      nullptr, nullptr, nullptr, nullptr, nullptr, deg, nullptr, nullptr, nullptr);
  k_applyproj<5, 4, 8, 2, true, false><<<MTB, 256, 0, stream>>>(
      h2h, h2l, nullptr, gsum, pe3, deg, Wa3h, Wa3l, ba3,
      nullptr, nullptr, Wpph, Wppl, nullptr, hsd, 128, 32);

  k_edge_out<<<cdiv(NE * 15, 256), 256, 0, stream>>>(src, dst, hsd, bp, out);
}